// Round 1
// baseline (235.600 us; speedup 1.0000x reference)
//
#include <hip/hip_runtime.h>

#define HW 256
#define HWMASK 255
#define CH 128
#define BATCH 8
#define NK 4
// conv tile
#define TS 64
#define LDW 76   // LDS row stride in floats: 304 B, 16B-aligned, non-pow2 bank spread

// ---------------- Kernel A: per-(b,c) mean of guidance ----------------
__global__ __launch_bounds__(256) void mean_kernel(const float* __restrict__ guid,
                                                   float* __restrict__ g) {
    int bc = blockIdx.x;
    const float4* p = (const float4*)(guid + (size_t)bc * (HW * HW));
    float s = 0.f;
    for (int i = threadIdx.x; i < (HW * HW / 4); i += 256) {
        float4 v = p[i];
        s += (v.x + v.y) + (v.z + v.w);
    }
    for (int off = 32; off > 0; off >>= 1) s += __shfl_down(s, off, 64);
    __shared__ float red[4];
    int lane = threadIdx.x & 63, wid = threadIdx.x >> 6;
    if (lane == 0) red[wid] = s;
    __syncthreads();
    if (threadIdx.x == 0) {
        float t = (red[0] + red[1]) + (red[2] + red[3]);
        g[bc] = t * (1.0f / 65536.0f);
    }
}

// ---------------- Kernel B: MLP + softmax -> weights[B][K] ----------------
__global__ __launch_bounds__(256) void mlp_kernel(const float* __restrict__ g,
                                                  const float* __restrict__ w1,
                                                  const float* __restrict__ b1,
                                                  const float* __restrict__ w2,
                                                  const float* __restrict__ b2,
                                                  float* __restrict__ wt) {
    __shared__ float gs[BATCH * CH];
    __shared__ float h1[BATCH * 32];
    __shared__ float lg[BATCH * NK];
    int t = threadIdx.x;
    for (int i = t; i < BATCH * CH; i += 256) gs[i] = g[i];
    __syncthreads();
    {   // 256 threads = 8 batches x 32 hidden units
        int b = t >> 5, j = t & 31;
        float acc = b1[j];
        #pragma unroll 4
        for (int c = 0; c < CH; ++c) acc += gs[b * CH + c] * w1[j * CH + c];
        h1[b * 32 + j] = fmaxf(acc, 0.f);
    }
    __syncthreads();
    if (t < BATCH * NK) {
        int b = t >> 2, k = t & 3;
        float acc = b2[k];
        #pragma unroll
        for (int j = 0; j < 32; ++j) acc += h1[b * 32 + j] * w2[k * 32 + j];
        lg[b * NK + k] = acc;
    }
    __syncthreads();
    if (t < BATCH) {
        int b = t;
        float m = lg[b * 4];
        for (int k = 1; k < 4; ++k) m = fmaxf(m, lg[b * 4 + k]);
        float e[4], s = 0.f;
        for (int k = 0; k < 4; ++k) { e[k] = expf(lg[b * 4 + k] - m); s += e[k]; }
        float inv = 1.0f / s;
        for (int k = 0; k < 4; ++k) wt[b * 4 + k] = e[k] * inv;
    }
}

// ---------------- Kernel C: dyn = blend of basis filters, stored FLIPPED ----------------
__global__ __launch_bounds__(256) void dyn_kernel(const float* __restrict__ wt,
                                                  const float* __restrict__ basis,
                                                  float* __restrict__ dynF) {
    int idx = blockIdx.x * 256 + threadIdx.x;
    if (idx >= BATCH * CH * 49) return;
    int ij = idx % 49;
    int bc = idx / 49;         // = b*CH + c
    int c = bc % CH;
    int b = bc / CH;
    float acc = 0.f;
    #pragma unroll
    for (int k = 0; k < NK; ++k)
        acc += wt[b * NK + k] * basis[(k * CH + c) * 49 + ij];
    // store flipped: (i,j) -> (6-i,6-j) is linear 48-ij
    dynF[bc * 49 + (48 - ij)] = acc;
}

// ---------------- Kernel D: circular depthwise 7x7 conv ----------------
__global__ __launch_bounds__(256) void conv_kernel(const float* __restrict__ x,
                                                   const float* __restrict__ dynF,
                                                   float* __restrict__ out) {
    int bc = blockIdx.z;
    int x0 = blockIdx.x * TS;
    int y0 = blockIdx.y * TS;
    __shared__ float lds[70 * LDW];
    const float* xp = x + (size_t)bc * (HW * HW);

    // filter taps: block-uniform address -> scalar loads
    const float* df = dynF + bc * 49;
    float d[49];
    #pragma unroll
    for (int i = 0; i < 49; ++i) d[i] = df[i];

    // stage 70x70 tile (3-halo each side, circular wrap)
    for (int e = threadIdx.x; e < 70 * 70; e += 256) {
        int r = e / 70, cc = e - r * 70;
        int gy = (y0 + r - 3) & HWMASK;
        int gx = (x0 + cc - 3) & HWMASK;
        lds[r * LDW + cc] = xp[gy * HW + gx];
    }
    __syncthreads();

    int tx = threadIdx.x & 15, ty = threadIdx.x >> 4;
    int lx0 = tx * 4, ly0 = ty * 4;
    float acc[4][4] = {};
    #pragma unroll
    for (int rr = 0; rr < 10; ++rr) {
        const float* row = &lds[(ly0 + rr) * LDW + lx0];
        float4 va = *(const float4*)(row);
        float4 vb = *(const float4*)(row + 4);
        float4 vc = *(const float4*)(row + 8);
        float v[12] = {va.x, va.y, va.z, va.w,
                       vb.x, vb.y, vb.z, vb.w,
                       vc.x, vc.y, vc.z, vc.w};
        #pragma unroll
        for (int r = 0; r < 4; ++r) {
            int ii = rr - r;
            if (ii >= 0 && ii <= 6) {
                #pragma unroll
                for (int q = 0; q < 4; ++q) {
                    #pragma unroll
                    for (int jj = 0; jj < 7; ++jj)
                        acc[r][q] += d[ii * 7 + jj] * v[q + jj];
                }
            }
        }
    }
    float* op = out + (size_t)bc * (HW * HW);
    #pragma unroll
    for (int r = 0; r < 4; ++r) {
        float4 o = {acc[r][0], acc[r][1], acc[r][2], acc[r][3]};
        *(float4*)&op[(y0 + ly0 + r) * HW + x0 + lx0] = o;
    }
}

extern "C" void kernel_launch(void* const* d_in, const int* in_sizes, int n_in,
                              void* d_out, int out_size, void* d_ws, size_t ws_size,
                              hipStream_t stream) {
    const float* x        = (const float*)d_in[0];
    const float* guidance = (const float*)d_in[1];
    const float* basis    = (const float*)d_in[2];
    const float* w1       = (const float*)d_in[3];
    const float* b1       = (const float*)d_in[4];
    const float* w2       = (const float*)d_in[5];
    const float* b2       = (const float*)d_in[6];
    float* out = (float*)d_out;
    float* ws  = (float*)d_ws;

    float* g    = ws;                 // 1024 floats
    float* wt   = ws + 1024;          // 32 floats
    float* dynF = ws + 1024 + 32;     // 50176 floats

    mean_kernel<<<BATCH * CH, 256, 0, stream>>>(guidance, g);
    mlp_kernel<<<1, 256, 0, stream>>>(g, w1, b1, w2, b2, wt);
    dyn_kernel<<<(BATCH * CH * 49 + 255) / 256, 256, 0, stream>>>(wt, basis, dynF);
    conv_kernel<<<dim3(HW / TS, HW / TS, BATCH * CH), 256, 0, stream>>>(x, dynF, out);
}

// Round 2
// 208.179 us; speedup vs baseline: 1.1317x; 1.1317x over previous
//
#include <hip/hip_runtime.h>

#define HW 256
#define HWMASK 255
#define CH 128
#define BATCH 8
#define NK 4
#define TS 64
#define LDQ 19   // float4 quads per LDS row (76 floats, 304B)

__device__ __forceinline__ int swz(int q, int s) { return q < 16 ? (q ^ s) : q; }
__device__ __forceinline__ int srow(int r) { return ((r >> 2) + r) & 7; }

// ---------------- Kernel A1: partial sums of guidance (4096 blocks, 16K floats each) ----
__global__ __launch_bounds__(256) void mean1_kernel(const float* __restrict__ guid,
                                                    float* __restrict__ partial) {
    int blk = blockIdx.x;
    const float4* p = (const float4*)(guid + (size_t)blk * 16384);
    float s = 0.f;
    for (int i = threadIdx.x; i < 4096; i += 256) {
        float4 v = p[i];
        s += (v.x + v.y) + (v.z + v.w);
    }
    for (int off = 32; off; off >>= 1) s += __shfl_down(s, off, 64);
    __shared__ float red[4];
    if ((threadIdx.x & 63) == 0) red[threadIdx.x >> 6] = s;
    __syncthreads();
    if (threadIdx.x == 0) partial[blk] = (red[0] + red[1]) + (red[2] + red[3]);
}

// ---------------- Kernel A2: finalize means ----------------
__global__ __launch_bounds__(256) void mean2_kernel(const float* __restrict__ partial,
                                                    float* __restrict__ g) {
    int bc = blockIdx.x * 256 + threadIdx.x;   // grid 4 -> 1024 bc
    float4 v = *(const float4*)(partial + bc * 4);
    g[bc] = ((v.x + v.y) + (v.z + v.w)) * (1.0f / 65536.0f);
}

// ---------------- Kernel B: MLP + softmax -> weights[B][K] ----------------
__global__ __launch_bounds__(256) void mlp_kernel(const float* __restrict__ g,
                                                  const float* __restrict__ w1,
                                                  const float* __restrict__ b1,
                                                  const float* __restrict__ w2,
                                                  const float* __restrict__ b2,
                                                  float* __restrict__ wt) {
    __shared__ float gs[BATCH * CH];
    __shared__ float h1[BATCH * 32];
    __shared__ float lg[BATCH * NK];
    int t = threadIdx.x;
    for (int i = t; i < BATCH * CH; i += 256) gs[i] = g[i];
    __syncthreads();
    {   // 256 threads = 8 batches x 32 hidden units
        int b = t >> 5, j = t & 31;
        float acc = b1[j];
        #pragma unroll 4
        for (int c = 0; c < CH; ++c) acc += gs[b * CH + c] * w1[j * CH + c];
        h1[b * 32 + j] = fmaxf(acc, 0.f);
    }
    __syncthreads();
    if (t < BATCH * NK) {
        int b = t >> 2, k = t & 3;
        float acc = b2[k];
        #pragma unroll
        for (int j = 0; j < 32; ++j) acc += h1[b * 32 + j] * w2[k * 32 + j];
        lg[b * NK + k] = acc;
    }
    __syncthreads();
    if (t < BATCH) {
        int b = t;
        float m = lg[b * 4];
        for (int k = 1; k < 4; ++k) m = fmaxf(m, lg[b * 4 + k]);
        float e[4], s = 0.f;
        for (int k = 0; k < 4; ++k) { e[k] = expf(lg[b * 4 + k] - m); s += e[k]; }
        float inv = 1.0f / s;
        for (int k = 0; k < 4; ++k) wt[b * 4 + k] = e[k] * inv;
    }
}

// ---------------- Kernel C: dyn = blend of basis filters, stored FLIPPED ----------------
__global__ __launch_bounds__(256) void dyn_kernel(const float* __restrict__ wt,
                                                  const float* __restrict__ basis,
                                                  float* __restrict__ dynF) {
    int idx = blockIdx.x * 256 + threadIdx.x;
    if (idx >= BATCH * CH * 49) return;
    int ij = idx % 49;
    int bc = idx / 49;
    int c = bc % CH;
    int b = bc / CH;
    float acc = 0.f;
    #pragma unroll
    for (int k = 0; k < NK; ++k)
        acc += wt[b * NK + k] * basis[(k * CH + c) * 49 + ij];
    dynF[bc * 49 + (48 - ij)] = acc;
}

// ---------------- Kernel D: circular depthwise 7x7 conv ----------------
__global__ __launch_bounds__(256) void conv_kernel(const float* __restrict__ x,
                                                   const float* __restrict__ dynF,
                                                   float* __restrict__ out) {
    int bc = blockIdx.z;
    int x0 = blockIdx.x * TS;
    int y0 = blockIdx.y * TS;
    __shared__ float4 lds4[70 * LDQ];
    const float* xp = x + (size_t)bc * (HW * HW);

    // filter taps: block-uniform address -> scalar loads into SGPRs
    const float* df = dynF + bc * 49;
    float d[49];
    #pragma unroll
    for (int i = 0; i < 49; ++i) d[i] = df[i];

    // stage 70 rows x 18 quads (LDS origin = global col x0-4, 16B aligned both sides)
    int tid = threadIdx.x;
    int c4 = tid % 18, r0 = tid / 18;
    if (r0 < 14) {
        int gx = (x0 - 4 + 4 * c4) & HWMASK;
        #pragma unroll
        for (int k = 0; k < 5; ++k) {
            int r = r0 + 14 * k;
            int gy = (y0 + r - 3) & HWMASK;
            float4 v = *(const float4*)(xp + gy * HW + gx);
            lds4[r * LDQ + swz(c4, srow(r))] = v;
        }
    }
    __syncthreads();

    int tx = tid & 15, ty = tid >> 4;
    int lx0 = tx * 4, ly0 = ty * 4;
    float acc[4][4] = {};
    #pragma unroll
    for (int rr = 0; rr < 10; ++rr) {
        int r = ly0 + rr;
        int s = srow(r);
        int rb = r * LDQ;
        float4 A  = lds4[rb + swz(tx,     s)];
        float4 Bv = lds4[rb + swz(tx + 1, s)];
        float4 Cv = lds4[rb + swz(tx + 2, s)];
        float v[12] = {A.x, A.y, A.z, A.w,
                       Bv.x, Bv.y, Bv.z, Bv.w,
                       Cv.x, Cv.y, Cv.z, Cv.w};
        #pragma unroll
        for (int rq = 0; rq < 4; ++rq) {
            int ii = rr - rq;
            if (ii >= 0 && ii <= 6) {
                #pragma unroll
                for (int q = 0; q < 4; ++q) {
                    #pragma unroll
                    for (int jj = 0; jj < 7; ++jj)
                        acc[rq][q] += d[ii * 7 + jj] * v[q + 1 + jj];
                }
            }
        }
    }
    float* op = out + (size_t)bc * (HW * HW);
    #pragma unroll
    for (int rq = 0; rq < 4; ++rq) {
        float4 o = {acc[rq][0], acc[rq][1], acc[rq][2], acc[rq][3]};
        *(float4*)&op[(y0 + ly0 + rq) * HW + x0 + lx0] = o;
    }
}

extern "C" void kernel_launch(void* const* d_in, const int* in_sizes, int n_in,
                              void* d_out, int out_size, void* d_ws, size_t ws_size,
                              hipStream_t stream) {
    const float* x        = (const float*)d_in[0];
    const float* guidance = (const float*)d_in[1];
    const float* basis    = (const float*)d_in[2];
    const float* w1       = (const float*)d_in[3];
    const float* b1       = (const float*)d_in[4];
    const float* w2       = (const float*)d_in[5];
    const float* b2       = (const float*)d_in[6];
    float* out = (float*)d_out;
    float* ws  = (float*)d_ws;

    float* g       = ws;                  // 1024
    float* wt      = ws + 1024;           // 32
    float* dynF    = ws + 1024 + 32;      // 50176
    float* partial = ws + 51232;          // 4096

    mean1_kernel<<<4096, 256, 0, stream>>>(guidance, partial);
    mean2_kernel<<<4, 256, 0, stream>>>(partial, g);
    mlp_kernel<<<1, 256, 0, stream>>>(g, w1, b1, w2, b2, wt);
    dyn_kernel<<<(BATCH * CH * 49 + 255) / 256, 256, 0, stream>>>(wt, basis, dynF);
    conv_kernel<<<dim3(HW / TS, HW / TS, BATCH * CH), 256, 0, stream>>>(x, dynF, out);
}